// Round 2
// baseline (1108.857 us; speedup 1.0000x reference)
//
#include <hip/hip_runtime.h>

#define N_NODES 100000
#define N_EDGES 1200000
#define D_IN 256
#define D_OUT 64

// ---------------------------------------------------------------------------
// Kernel 1: support = X @ W  — LDS-tiled, register-blocked f32.
// Block: 256 threads, tile 128 rows x 64 cols, K-tile 64.
// Thread (ty,tx) = (t/8, t%8) computes rows {ty+32*rr} x cols {tx+8*cc},
// rr<4, cc<8.  Strided row/col mapping + stride-68 LDS padding makes every
// ds_read_b128 hit 8 distinct banks (8-lane broadcast each) — conflict-free.
// ---------------------------------------------------------------------------
__global__ __launch_bounds__(256, 3) void gemm_xw(const float* __restrict__ X,
                                                  const float* __restrict__ W,
                                                  float* __restrict__ support) {
    __shared__ float Xs[128][68];
    __shared__ float Wt[64][68];

    const int t = threadIdx.x;
    const int ty = t >> 3;          // 0..31
    const int tx = t & 7;           // 0..7
    const int row0 = blockIdx.x * 128;

    float acc[4][8];
#pragma unroll
    for (int rr = 0; rr < 4; ++rr)
#pragma unroll
        for (int cc = 0; cc < 8; ++cc) acc[rr][cc] = 0.0f;

    for (int kt = 0; kt < 4; ++kt) {
        const int k0 = kt * 64;

        // Stage Xs[128][64]: 2048 float4, 8 per thread, fully coalesced.
#pragma unroll
        for (int p = 0; p < 8; ++p) {
            int idx = t + p * 256;
            int row = idx >> 4;      // 0..127
            int kq  = idx & 15;      // 0..15 (float4 within row)
            float4 v = {0.0f, 0.0f, 0.0f, 0.0f};
            int grow = row0 + row;
            if (grow < N_NODES)
                v = *reinterpret_cast<const float4*>(X + (size_t)grow * D_IN + k0 + kq * 4);
            *reinterpret_cast<float4*>(&Xs[row][kq * 4]) = v;
        }

        // Stage Wt[64][64] = transpose of W[k0:k0+64][:]: 1024 float4, 4/thread.
#pragma unroll
        for (int p = 0; p < 4; ++p) {
            int idx = t + p * 256;
            int k  = idx >> 4;       // 0..63
            int cq = idx & 15;       // 0..15
            float4 v = *reinterpret_cast<const float4*>(W + (size_t)(k0 + k) * D_OUT + cq * 4);
            Wt[cq * 4 + 0][k] = v.x;
            Wt[cq * 4 + 1][k] = v.y;
            Wt[cq * 4 + 2][k] = v.z;
            Wt[cq * 4 + 3][k] = v.w;
        }
        __syncthreads();

#pragma unroll 4
        for (int kk = 0; kk < 16; ++kk) {
            float4 xv[4], wv[8];
#pragma unroll
            for (int rr = 0; rr < 4; ++rr)
                xv[rr] = *reinterpret_cast<const float4*>(&Xs[ty + 32 * rr][kk * 4]);
#pragma unroll
            for (int cc = 0; cc < 8; ++cc)
                wv[cc] = *reinterpret_cast<const float4*>(&Wt[tx + 8 * cc][kk * 4]);
#pragma unroll
            for (int rr = 0; rr < 4; ++rr)
#pragma unroll
                for (int cc = 0; cc < 8; ++cc) {
                    acc[rr][cc] = fmaf(xv[rr].x, wv[cc].x, acc[rr][cc]);
                    acc[rr][cc] = fmaf(xv[rr].y, wv[cc].y, acc[rr][cc]);
                    acc[rr][cc] = fmaf(xv[rr].z, wv[cc].z, acc[rr][cc]);
                    acc[rr][cc] = fmaf(xv[rr].w, wv[cc].w, acc[rr][cc]);
                }
        }
        __syncthreads();
    }

#pragma unroll
    for (int rr = 0; rr < 4; ++rr) {
        int grow = row0 + ty + 32 * rr;
        if (grow < N_NODES) {
#pragma unroll
            for (int cc = 0; cc < 8; ++cc)
                support[(size_t)grow * D_OUT + tx + 8 * cc] = acc[rr][cc];
        }
    }
}

// ---------------------------------------------------------------------------
// Kernel 2: zero d_out.
// ---------------------------------------------------------------------------
__global__ void zero_out(float4* __restrict__ out, int n4) {
    int i = blockIdx.x * blockDim.x + threadIdx.x;
    int stride = gridDim.x * blockDim.x;
    for (; i < n4; i += stride) out[i] = float4{0.0f, 0.0f, 0.0f, 0.0f};
}

// ---------------------------------------------------------------------------
// Kernel 3: COO scatter-add, 4 edges processed concurrently per wave.
// lane = 16*q + s:  q = edge slot (4 edges in flight), s = column quad.
// Each lane gathers float4 of support[col] and issues 4 atomicAdds.
// Serial chain per 64-edge chunk: 16 iterations (was 64).
// ---------------------------------------------------------------------------
__global__ __launch_bounds__(256) void spmm_scatter(const int* __restrict__ rows,
                                                    const int* __restrict__ cols,
                                                    const float* __restrict__ vals,
                                                    const float* __restrict__ support,
                                                    float* __restrict__ out,
                                                    int n_edges) {
    const int lane = threadIdx.x & 63;
    const int q = lane >> 4;     // 0..3: which of 4 concurrent edges
    const int s = lane & 15;     // 0..15: float4 index within D_OUT
    const int wave_global = (int)((blockIdx.x * blockDim.x + threadIdx.x) >> 6);
    const int n_waves = (int)((gridDim.x * blockDim.x) >> 6);

    for (int base = wave_global * 64; base < n_edges; base += n_waves * 64) {
        int my_e = base + lane;   // N_EDGES % 64 == 0 -> always valid
        int r = rows[my_e];
        int c = cols[my_e];
        float v = vals[my_e];

#pragma unroll 4
        for (int i = 0; i < 16; ++i) {
            int src = i * 4 + q;
            int row = __shfl(r, src);
            int col = __shfl(c, src);
            float val = __shfl(v, src);
            float4 sv = *reinterpret_cast<const float4*>(support + (size_t)col * D_OUT + s * 4);
            float* op = out + (size_t)row * D_OUT + s * 4;
            atomicAdd(op + 0, val * sv.x);
            atomicAdd(op + 1, val * sv.y);
            atomicAdd(op + 2, val * sv.z);
            atomicAdd(op + 3, val * sv.w);
        }
    }
}

extern "C" void kernel_launch(void* const* d_in, const int* in_sizes, int n_in,
                              void* d_out, int out_size, void* d_ws, size_t ws_size,
                              hipStream_t stream) {
    const float* X      = (const float*)d_in[0];
    const float* W      = (const float*)d_in[1];
    const int*   A_rows = (const int*)d_in[2];
    const int*   A_cols = (const int*)d_in[3];
    const float* A_vals = (const float*)d_in[4];
    float* out = (float*)d_out;
    float* support = (float*)d_ws;  // 25.6 MB scratch

    // out = 0 (harness poisons with 0xAA)
    {
        int n4 = (N_NODES * D_OUT) / 4;
        zero_out<<<2048, 256, 0, stream>>>((float4*)out, n4);
    }

    // support = X @ W
    {
        int nblocks = (N_NODES + 127) / 128;  // 782
        gemm_xw<<<nblocks, 256, 0, stream>>>(X, W, support);
    }

    // out[row] += val * support[col] per edge
    {
        int chunks = N_EDGES / 64;            // 18750
        int nblocks = (chunks + 3) / 4;       // 4 waves/block
        spmm_scatter<<<nblocks, 256, 0, stream>>>(A_rows, A_cols, A_vals, support,
                                                  out, N_EDGES);
    }
}

// Round 3
// 303.989 us; speedup vs baseline: 3.6477x; 3.6477x over previous
//
#include <hip/hip_runtime.h>

#define N_NODES 100000
#define N_EDGES 1200000
#define D_IN 256
#define D_OUT 64

// ---- workspace layout (bytes) ----------------------------------------------
#define OFF_SUPPORT   0u                 // 100000*64*4 = 25,600,000
#define OFF_ROWSTART  25600000u          // (N_NODES+1)*4 -> padded 400,016
#define OFF_COUNTS    26000016u          // 400,000
#define OFF_FILL      26400016u          // 400,000
#define OFF_EDGES     26800016u          // 1.2M * 8B (uint2) = 9,600,000
#define OFF_BLKSUMS   36400016u          // 512*4 = 2,048
#define WS_NEEDED     36402064u

// ---------------------------------------------------------------------------
// Kernel: support = X @ W  — LDS-tiled, register-blocked f32 (unchanged R1).
// ---------------------------------------------------------------------------
__global__ __launch_bounds__(256, 3) void gemm_xw(const float* __restrict__ X,
                                                  const float* __restrict__ W,
                                                  float* __restrict__ support) {
    __shared__ float Xs[128][68];
    __shared__ float Wt[64][68];

    const int t = threadIdx.x;
    const int ty = t >> 3;          // 0..31
    const int tx = t & 7;           // 0..7
    const int row0 = blockIdx.x * 128;

    float acc[4][8];
#pragma unroll
    for (int rr = 0; rr < 4; ++rr)
#pragma unroll
        for (int cc = 0; cc < 8; ++cc) acc[rr][cc] = 0.0f;

    for (int kt = 0; kt < 4; ++kt) {
        const int k0 = kt * 64;

#pragma unroll
        for (int p = 0; p < 8; ++p) {
            int idx = t + p * 256;
            int row = idx >> 4;
            int kq  = idx & 15;
            float4 v = {0.0f, 0.0f, 0.0f, 0.0f};
            int grow = row0 + row;
            if (grow < N_NODES)
                v = *reinterpret_cast<const float4*>(X + (size_t)grow * D_IN + k0 + kq * 4);
            *reinterpret_cast<float4*>(&Xs[row][kq * 4]) = v;
        }

#pragma unroll
        for (int p = 0; p < 4; ++p) {
            int idx = t + p * 256;
            int k  = idx >> 4;
            int cq = idx & 15;
            float4 v = *reinterpret_cast<const float4*>(W + (size_t)(k0 + k) * D_OUT + cq * 4);
            Wt[cq * 4 + 0][k] = v.x;
            Wt[cq * 4 + 1][k] = v.y;
            Wt[cq * 4 + 2][k] = v.z;
            Wt[cq * 4 + 3][k] = v.w;
        }
        __syncthreads();

#pragma unroll 4
        for (int kk = 0; kk < 16; ++kk) {
            float4 xv[4], wv[8];
#pragma unroll
            for (int rr = 0; rr < 4; ++rr)
                xv[rr] = *reinterpret_cast<const float4*>(&Xs[ty + 32 * rr][kk * 4]);
#pragma unroll
            for (int cc = 0; cc < 8; ++cc)
                wv[cc] = *reinterpret_cast<const float4*>(&Wt[tx + 8 * cc][kk * 4]);
#pragma unroll
            for (int rr = 0; rr < 4; ++rr)
#pragma unroll
                for (int cc = 0; cc < 8; ++cc) {
                    acc[rr][cc] = fmaf(xv[rr].x, wv[cc].x, acc[rr][cc]);
                    acc[rr][cc] = fmaf(xv[rr].y, wv[cc].y, acc[rr][cc]);
                    acc[rr][cc] = fmaf(xv[rr].z, wv[cc].z, acc[rr][cc]);
                    acc[rr][cc] = fmaf(xv[rr].w, wv[cc].w, acc[rr][cc]);
                }
        }
        __syncthreads();
    }

#pragma unroll
    for (int rr = 0; rr < 4; ++rr) {
        int grow = row0 + ty + 32 * rr;
        if (grow < N_NODES) {
#pragma unroll
            for (int cc = 0; cc < 8; ++cc)
                support[(size_t)grow * D_OUT + tx + 8 * cc] = acc[rr][cc];
        }
    }
}

// ---------------------------------------------------------------------------
// CSR build
// ---------------------------------------------------------------------------
__global__ void zero_ints(int* __restrict__ a, int n) {
    int i = blockIdx.x * blockDim.x + threadIdx.x;
    int stride = gridDim.x * blockDim.x;
    for (; i < n; i += stride) a[i] = 0;
}

__global__ void hist_rows(const int* __restrict__ rows, int* __restrict__ counts) {
    int i = blockIdx.x * blockDim.x + threadIdx.x;
    int stride = gridDim.x * blockDim.x;
    for (; i < N_EDGES; i += stride) atomicAdd(&counts[rows[i]], 1);
}

// Level-1 exclusive scan: 256-wide blocks, Hillis-Steele in LDS.
__global__ __launch_bounds__(256) void scan_l1(const int* __restrict__ counts,
                                               int* __restrict__ row_start,
                                               int* __restrict__ blkSums) {
    __shared__ int s[256];
    const int t = threadIdx.x;
    const int i = blockIdx.x * 256 + t;
    int v = (i < N_NODES) ? counts[i] : 0;
    s[t] = v;
    __syncthreads();
#pragma unroll
    for (int off = 1; off < 256; off <<= 1) {
        int x = (t >= off) ? s[t - off] : 0;
        __syncthreads();
        s[t] += x;
        __syncthreads();
    }
    if (i < N_NODES) row_start[i] = s[t] - v;   // exclusive prefix
    if (t == 255) blkSums[blockIdx.x] = s[255]; // block total
}

// Level-2: single block scans the (<=512) block sums in place -> exclusive.
__global__ __launch_bounds__(512) void scan_l2(int* __restrict__ blkSums, int nblk) {
    __shared__ int s[512];
    const int t = threadIdx.x;
    int v = (t < nblk) ? blkSums[t] : 0;
    s[t] = v;
    __syncthreads();
#pragma unroll
    for (int off = 1; off < 512; off <<= 1) {
        int x = (t >= off) ? s[t - off] : 0;
        __syncthreads();
        s[t] += x;
        __syncthreads();
    }
    if (t < nblk) blkSums[t] = s[t] - v;        // exclusive
}

__global__ __launch_bounds__(256) void scan_l3(int* __restrict__ row_start,
                                               const int* __restrict__ blkSums) {
    const int i = blockIdx.x * 256 + threadIdx.x;
    if (i < N_NODES) row_start[i] += blkSums[blockIdx.x];
    if (i == 0) row_start[N_NODES] = N_EDGES;
}

// Reorder edges into row-sorted order; pack (col, val) into one 8B store.
__global__ void reorder_edges(const int* __restrict__ rows,
                              const int* __restrict__ cols,
                              const float* __restrict__ vals,
                              const int* __restrict__ row_start,
                              int* __restrict__ fill,
                              uint2* __restrict__ edge_s) {
    int i = blockIdx.x * blockDim.x + threadIdx.x;
    int stride = gridDim.x * blockDim.x;
    for (; i < N_EDGES; i += stride) {
        int r = rows[i];
        int pos = row_start[r] + atomicAdd(&fill[r], 1);
        edge_s[pos] = make_uint2((unsigned)cols[i], __float_as_uint(vals[i]));
    }
}

// ---------------------------------------------------------------------------
// Gather: one wave per output row. Coalesced 256B support reads, zero atomics,
// out written exactly once. 2-wide unroll keeps two gathers in flight.
// ---------------------------------------------------------------------------
__global__ __launch_bounds__(256) void spmm_gather(const uint2* __restrict__ edge_s,
                                                   const int* __restrict__ row_start,
                                                   const float* __restrict__ support,
                                                   float* __restrict__ out) {
    const int r = blockIdx.x * 4 + (threadIdx.x >> 6);
    if (r >= N_NODES) return;
    const int lane = threadIdx.x & 63;

    int e   = row_start[r];
    int end = row_start[r + 1];
    float acc = 0.0f;

    for (; e + 1 < end; e += 2) {
        uint2 p0 = edge_s[e];
        uint2 p1 = edge_s[e + 1];
        float s0 = support[(size_t)p0.x * D_OUT + lane];
        float s1 = support[(size_t)p1.x * D_OUT + lane];
        acc = fmaf(__uint_as_float(p0.y), s0, acc);
        acc = fmaf(__uint_as_float(p1.y), s1, acc);
    }
    if (e < end) {
        uint2 p = edge_s[e];
        acc = fmaf(__uint_as_float(p.y), support[(size_t)p.x * D_OUT + lane], acc);
    }
    out[(size_t)r * D_OUT + lane] = acc;
}

// ---------------------------------------------------------------------------
// Fallback path (ws too small): zero + R0-style atomic scatter.
// ---------------------------------------------------------------------------
__global__ void zero_out(float4* __restrict__ out, int n4) {
    int i = blockIdx.x * blockDim.x + threadIdx.x;
    int stride = gridDim.x * blockDim.x;
    for (; i < n4; i += stride) out[i] = float4{0.0f, 0.0f, 0.0f, 0.0f};
}

__global__ __launch_bounds__(256) void spmm_scatter(const int* __restrict__ rows,
                                                    const int* __restrict__ cols,
                                                    const float* __restrict__ vals,
                                                    const float* __restrict__ support,
                                                    float* __restrict__ out,
                                                    int n_edges) {
    const int lane = threadIdx.x & 63;
    const int wave_global = (int)((blockIdx.x * blockDim.x + threadIdx.x) >> 6);
    const int n_waves = (int)((gridDim.x * blockDim.x) >> 6);

    for (int base = wave_global * 64; base < n_edges; base += n_waves * 64) {
        int my_e = base + lane;
        int r = rows[my_e];
        int c = cols[my_e];
        float v = vals[my_e];

        int cnt = min(64, n_edges - base);
        for (int i = 0; i < cnt; ++i) {
            int row = __shfl(r, i);
            int col = __shfl(c, i);
            float val = __shfl(v, i);
            float s = support[(size_t)col * D_OUT + lane];
            atomicAdd(&out[(size_t)row * D_OUT + lane], val * s);
        }
    }
}

extern "C" void kernel_launch(void* const* d_in, const int* in_sizes, int n_in,
                              void* d_out, int out_size, void* d_ws, size_t ws_size,
                              hipStream_t stream) {
    const float* X      = (const float*)d_in[0];
    const float* W      = (const float*)d_in[1];
    const int*   A_rows = (const int*)d_in[2];
    const int*   A_cols = (const int*)d_in[3];
    const float* A_vals = (const float*)d_in[4];
    float* out = (float*)d_out;

    char* ws = (char*)d_ws;
    float* support   = (float*)(ws + OFF_SUPPORT);

    const int gemm_blocks = (N_NODES + 127) / 128;  // 782

    if (ws_size >= (size_t)WS_NEEDED) {
        int*   row_start = (int*)(ws + OFF_ROWSTART);
        int*   counts    = (int*)(ws + OFF_COUNTS);
        int*   fill      = (int*)(ws + OFF_FILL);
        uint2* edge_s    = (uint2*)(ws + OFF_EDGES);
        int*   blkSums   = (int*)(ws + OFF_BLKSUMS);

        const int nblk_scan = (N_NODES + 255) / 256;  // 391

        // CSR build
        zero_ints<<<256, 256, 0, stream>>>(counts, 2 * 400000 / 4);  // counts+fill (contiguous)
        hist_rows<<<1024, 256, 0, stream>>>(A_rows, counts);
        scan_l1<<<nblk_scan, 256, 0, stream>>>(counts, row_start, blkSums);
        scan_l2<<<1, 512, 0, stream>>>(blkSums, nblk_scan);
        scan_l3<<<nblk_scan, 256, 0, stream>>>(row_start, blkSums);
        reorder_edges<<<1024, 256, 0, stream>>>(A_rows, A_cols, A_vals, row_start,
                                                fill, edge_s);

        // support = X @ W
        gemm_xw<<<gemm_blocks, 256, 0, stream>>>(X, W, support);

        // out = A @ support (gather, no atomics)
        spmm_gather<<<(N_NODES + 3) / 4, 256, 0, stream>>>(edge_s, row_start,
                                                           support, out);
    } else {
        // Fallback: atomic scatter (R0 pattern)
        int n4 = (N_NODES * D_OUT) / 4;
        zero_out<<<2048, 256, 0, stream>>>((float4*)out, n4);
        gemm_xw<<<gemm_blocks, 256, 0, stream>>>(X, W, support);
        int chunks = N_EDGES / 64;
        spmm_scatter<<<(chunks + 3) / 4, 256, 0, stream>>>(A_rows, A_cols, A_vals,
                                                           support, out, N_EDGES);
    }
}

// Round 4
// 292.619 us; speedup vs baseline: 3.7894x; 1.0389x over previous
//
#include <hip/hip_runtime.h>

#define N_NODES 100000
#define N_EDGES 1200000
#define D_IN 256
#define D_OUT 64

// ---- workspace layout (bytes) ----------------------------------------------
#define OFF_SUPPORT   0u                 // bf16: 100000*64*2 = 12,800,000
#define OFF_ROWSTART  12800000u          // (N_NODES+1)*4 -> padded 400,016
#define OFF_COUNTS    13200016u          // 400,000
#define OFF_FILL      13600016u          // 400,000
#define OFF_EDGES     14000016u          // 1.2M * 8B (uint2) = 9,600,000 (8B-aligned)
#define OFF_BLKSUMS   23600016u          // 512*4
#define WS_NEEDED     23602064u

static __device__ __forceinline__ ushort f32_to_bf16_rne(float f) {
    unsigned bits = __float_as_uint(f);
    unsigned r = (bits + 0x7FFFu + ((bits >> 16) & 1u)) >> 16;
    return (ushort)r;
}
static __device__ __forceinline__ float bf16_to_f32(ushort u) {
    return __uint_as_float((unsigned)u << 16);
}

// ---------------------------------------------------------------------------
// Kernel: support(bf16) = X @ W — LDS-tiled, register-blocked f32.
// Change vs R3: W staged via REGISTER TRANSPOSE (4 scalar global loads ->
// one float4 LDS store). Store lane mapping spans 8 cols x 8 k-quads per
// instruction -> exactly 8 lanes per bank-quad (the 8-cycle minimum for a
// 1KiB wave store) — kills the 2.8M SQ_LDS_BANK_CONFLICT from R3's scalar
// transpose stores. Compute loop & Xs staging unchanged (both conflict-free).
// ---------------------------------------------------------------------------
__global__ __launch_bounds__(256, 3) void gemm_xw(const float* __restrict__ X,
                                                  const float* __restrict__ W,
                                                  ushort* __restrict__ support) {
    __shared__ float Xs[128][68];
    __shared__ float Wt[64][68];   // Wt[col][k] within the 64-wide K tile

    const int t = threadIdx.x;
    const int ty = t >> 3;          // 0..31
    const int tx = t & 7;           // 0..7
    const int row0 = blockIdx.x * 128;

    // W staging mapping: lane -> (col low bits, k-quad)
    const int wb  = t & 7;          // col & 7
    const int wq  = (t >> 3) & 15;  // k-quad 0..15
    const int wch = t >> 7;         // 0..1 (col high chunk)

    float acc[4][8];
#pragma unroll
    for (int rr = 0; rr < 4; ++rr)
#pragma unroll
        for (int cc = 0; cc < 8; ++cc) acc[rr][cc] = 0.0f;

    for (int kt = 0; kt < 4; ++kt) {
        const int k0 = kt * 64;

        // Stage Xs[128][64]: 8 float4 per thread, coalesced, even bank spread.
#pragma unroll
        for (int p = 0; p < 8; ++p) {
            int idx = t + p * 256;
            int row = idx >> 4;
            int kq  = idx & 15;
            float4 v = {0.0f, 0.0f, 0.0f, 0.0f};
            int grow = row0 + row;
            if (grow < N_NODES)
                v = *reinterpret_cast<const float4*>(X + (size_t)grow * D_IN + k0 + kq * 4);
            *reinterpret_cast<float4*>(&Xs[row][kq * 4]) = v;
        }

        // Stage Wt[64][64] via register transpose: per p, this thread owns
        // column c = wb + 8*(wch*4+p) and k-quad wq.
#pragma unroll
        for (int p = 0; p < 4; ++p) {
            int c = wb + 8 * (wch * 4 + p);        // 0..63
            int k = k0 + wq * 4;
            float4 v;
            v.x = W[(size_t)(k + 0) * D_OUT + c];
            v.y = W[(size_t)(k + 1) * D_OUT + c];
            v.z = W[(size_t)(k + 2) * D_OUT + c];
            v.w = W[(size_t)(k + 3) * D_OUT + c];
            *reinterpret_cast<float4*>(&Wt[c][wq * 4]) = v;
        }
        __syncthreads();

#pragma unroll 4
        for (int kk = 0; kk < 16; ++kk) {
            float4 xv[4], wv[8];
#pragma unroll
            for (int rr = 0; rr < 4; ++rr)
                xv[rr] = *reinterpret_cast<const float4*>(&Xs[ty + 32 * rr][kk * 4]);
#pragma unroll
            for (int cc = 0; cc < 8; ++cc)
                wv[cc] = *reinterpret_cast<const float4*>(&Wt[tx + 8 * cc][kk * 4]);
#pragma unroll
            for (int rr = 0; rr < 4; ++rr)
#pragma unroll
                for (int cc = 0; cc < 8; ++cc) {
                    acc[rr][cc] = fmaf(xv[rr].x, wv[cc].x, acc[rr][cc]);
                    acc[rr][cc] = fmaf(xv[rr].y, wv[cc].y, acc[rr][cc]);
                    acc[rr][cc] = fmaf(xv[rr].z, wv[cc].z, acc[rr][cc]);
                    acc[rr][cc] = fmaf(xv[rr].w, wv[cc].w, acc[rr][cc]);
                }
        }
        __syncthreads();
    }

#pragma unroll
    for (int rr = 0; rr < 4; ++rr) {
        int grow = row0 + ty + 32 * rr;
        if (grow < N_NODES) {
#pragma unroll
            for (int cc = 0; cc < 8; ++cc)
                support[(size_t)grow * D_OUT + tx + 8 * cc] = f32_to_bf16_rne(acc[rr][cc]);
        }
    }
}

// ---------------------------------------------------------------------------
// CSR build
// ---------------------------------------------------------------------------
__global__ void zero_ints(int* __restrict__ a, int n) {
    int i = blockIdx.x * blockDim.x + threadIdx.x;
    int stride = gridDim.x * blockDim.x;
    for (; i < n; i += stride) a[i] = 0;
}

__global__ void hist_rows(const int* __restrict__ rows, int* __restrict__ counts) {
    int i = blockIdx.x * blockDim.x + threadIdx.x;
    int stride = gridDim.x * blockDim.x;
    for (; i < N_EDGES; i += stride) atomicAdd(&counts[rows[i]], 1);
}

__global__ __launch_bounds__(256) void scan_l1(const int* __restrict__ counts,
                                               int* __restrict__ row_start,
                                               int* __restrict__ blkSums) {
    __shared__ int s[256];
    const int t = threadIdx.x;
    const int i = blockIdx.x * 256 + t;
    int v = (i < N_NODES) ? counts[i] : 0;
    s[t] = v;
    __syncthreads();
#pragma unroll
    for (int off = 1; off < 256; off <<= 1) {
        int x = (t >= off) ? s[t - off] : 0;
        __syncthreads();
        s[t] += x;
        __syncthreads();
    }
    if (i < N_NODES) row_start[i] = s[t] - v;
    if (t == 255) blkSums[blockIdx.x] = s[255];
}

__global__ __launch_bounds__(512) void scan_l2(int* __restrict__ blkSums, int nblk) {
    __shared__ int s[512];
    const int t = threadIdx.x;
    int v = (t < nblk) ? blkSums[t] : 0;
    s[t] = v;
    __syncthreads();
#pragma unroll
    for (int off = 1; off < 512; off <<= 1) {
        int x = (t >= off) ? s[t - off] : 0;
        __syncthreads();
        s[t] += x;
        __syncthreads();
    }
    if (t < nblk) blkSums[t] = s[t] - v;
}

__global__ __launch_bounds__(256) void scan_l3(int* __restrict__ row_start,
                                               const int* __restrict__ blkSums) {
    const int i = blockIdx.x * 256 + threadIdx.x;
    if (i < N_NODES) row_start[i] += blkSums[blockIdx.x];
    if (i == 0) row_start[N_NODES] = N_EDGES;
}

__global__ void reorder_edges(const int* __restrict__ rows,
                              const int* __restrict__ cols,
                              const float* __restrict__ vals,
                              const int* __restrict__ row_start,
                              int* __restrict__ fill,
                              uint2* __restrict__ edge_s) {
    int i = blockIdx.x * blockDim.x + threadIdx.x;
    int stride = gridDim.x * blockDim.x;
    for (; i < N_EDGES; i += stride) {
        int r = rows[i];
        int pos = row_start[r] + atomicAdd(&fill[r], 1);
        edge_s[pos] = make_uint2((unsigned)cols[i], __float_as_uint(vals[i]));
    }
}

// ---------------------------------------------------------------------------
// Gather: one wave per output row; bf16 support halves gather traffic.
// ---------------------------------------------------------------------------
__global__ __launch_bounds__(256) void spmm_gather(const uint2* __restrict__ edge_s,
                                                   const int* __restrict__ row_start,
                                                   const ushort* __restrict__ support,
                                                   float* __restrict__ out) {
    const int r = blockIdx.x * 4 + (threadIdx.x >> 6);
    if (r >= N_NODES) return;
    const int lane = threadIdx.x & 63;

    int e   = row_start[r];
    int end = row_start[r + 1];
    float acc = 0.0f;

    for (; e + 1 < end; e += 2) {
        uint2 p0 = edge_s[e];
        uint2 p1 = edge_s[e + 1];
        float s0 = bf16_to_f32(support[(size_t)p0.x * D_OUT + lane]);
        float s1 = bf16_to_f32(support[(size_t)p1.x * D_OUT + lane]);
        acc = fmaf(__uint_as_float(p0.y), s0, acc);
        acc = fmaf(__uint_as_float(p1.y), s1, acc);
    }
    if (e < end) {
        uint2 p = edge_s[e];
        acc = fmaf(__uint_as_float(p.y), bf16_to_f32(support[(size_t)p.x * D_OUT + lane]), acc);
    }
    out[(size_t)r * D_OUT + lane] = acc;
}

// ---------------------------------------------------------------------------
// Fallback path (ws too small): zero + atomic scatter from bf16 support.
// ---------------------------------------------------------------------------
__global__ void zero_out(float4* __restrict__ out, int n4) {
    int i = blockIdx.x * blockDim.x + threadIdx.x;
    int stride = gridDim.x * blockDim.x;
    for (; i < n4; i += stride) out[i] = float4{0.0f, 0.0f, 0.0f, 0.0f};
}

__global__ __launch_bounds__(256) void spmm_scatter(const int* __restrict__ rows,
                                                    const int* __restrict__ cols,
                                                    const float* __restrict__ vals,
                                                    const ushort* __restrict__ support,
                                                    float* __restrict__ out,
                                                    int n_edges) {
    const int lane = threadIdx.x & 63;
    const int wave_global = (int)((blockIdx.x * blockDim.x + threadIdx.x) >> 6);
    const int n_waves = (int)((gridDim.x * blockDim.x) >> 6);

    for (int base = wave_global * 64; base < n_edges; base += n_waves * 64) {
        int my_e = base + lane;
        int r = rows[my_e];
        int c = cols[my_e];
        float v = vals[my_e];

        int cnt = min(64, n_edges - base);
        for (int i = 0; i < cnt; ++i) {
            int row = __shfl(r, i);
            int col = __shfl(c, i);
            float val = __shfl(v, i);
            float s = bf16_to_f32(support[(size_t)col * D_OUT + lane]);
            atomicAdd(&out[(size_t)row * D_OUT + lane], val * s);
        }
    }
}

extern "C" void kernel_launch(void* const* d_in, const int* in_sizes, int n_in,
                              void* d_out, int out_size, void* d_ws, size_t ws_size,
                              hipStream_t stream) {
    const float* X      = (const float*)d_in[0];
    const float* W      = (const float*)d_in[1];
    const int*   A_rows = (const int*)d_in[2];
    const int*   A_cols = (const int*)d_in[3];
    const float* A_vals = (const float*)d_in[4];
    float* out = (float*)d_out;

    char* ws = (char*)d_ws;
    ushort* support = (ushort*)(ws + OFF_SUPPORT);

    const int gemm_blocks = (N_NODES + 127) / 128;  // 782

    if (ws_size >= (size_t)WS_NEEDED) {
        int*   row_start = (int*)(ws + OFF_ROWSTART);
        int*   counts    = (int*)(ws + OFF_COUNTS);
        int*   fill      = (int*)(ws + OFF_FILL);
        uint2* edge_s    = (uint2*)(ws + OFF_EDGES);
        int*   blkSums   = (int*)(ws + OFF_BLKSUMS);

        const int nblk_scan = (N_NODES + 255) / 256;  // 391

        // CSR build
        zero_ints<<<256, 256, 0, stream>>>(counts, 2 * 400000 / 4);  // counts+fill
        hist_rows<<<1024, 256, 0, stream>>>(A_rows, counts);
        scan_l1<<<nblk_scan, 256, 0, stream>>>(counts, row_start, blkSums);
        scan_l2<<<1, 512, 0, stream>>>(blkSums, nblk_scan);
        scan_l3<<<nblk_scan, 256, 0, stream>>>(row_start, blkSums);
        reorder_edges<<<1024, 256, 0, stream>>>(A_rows, A_cols, A_vals, row_start,
                                                fill, edge_s);

        // support = bf16(X @ W)
        gemm_xw<<<gemm_blocks, 256, 0, stream>>>(X, W, support);

        // out = A @ support (gather, no atomics)
        spmm_gather<<<(N_NODES + 3) / 4, 256, 0, stream>>>(edge_s, row_start,
                                                           support, out);
    } else {
        int n4 = (N_NODES * D_OUT) / 4;
        zero_out<<<2048, 256, 0, stream>>>((float4*)out, n4);
        gemm_xw<<<gemm_blocks, 256, 0, stream>>>(X, W, support);
        int chunks = N_EDGES / 64;
        spmm_scatter<<<(chunks + 3) / 4, 256, 0, stream>>>(A_rows, A_cols, A_vals,
                                                           support, out, N_EDGES);
    }
}

// Round 5
// 248.863 us; speedup vs baseline: 4.4557x; 1.1758x over previous
//
#include <hip/hip_runtime.h>

#define N_NODES 100000
#define N_EDGES 1200000
#define D_IN 256
#define D_OUT 64

// ---- workspace layout (bytes) ----------------------------------------------
#define OFF_SUPPORT   0u                 // bf16: 100000*64*2 = 12,800,000
#define OFF_ROWSTART  12800000u          // (N_NODES+1)*4 -> padded 400,016
#define OFF_COUNTS    13200016u          // 400,000
#define OFF_FILL      13600016u          // 400,000
#define OFF_EDGES     14000016u          // 1.2M * 8B (uint2) = 9,600,000
#define OFF_BLKSUMS   23600016u          // 512*4
#define WS_NEEDED     23602064u

using bf16x8 = __attribute__((ext_vector_type(8))) short;
using f32x4  = __attribute__((ext_vector_type(4))) float;

static __device__ __forceinline__ ushort f32_to_bf16_rne(float f) {
    unsigned bits = __float_as_uint(f);
    unsigned r = (bits + 0x7FFFu + ((bits >> 16) & 1u)) >> 16;
    return (ushort)r;
}
static __device__ __forceinline__ float bf16_to_f32(ushort u) {
    return __uint_as_float((unsigned)u << 16);
}
static __device__ __forceinline__ unsigned pack2bf(float a, float b) {
    return (unsigned)f32_to_bf16_rne(a) | ((unsigned)f32_to_bf16_rne(b) << 16);
}

// ---------------------------------------------------------------------------
// Kernel: support(bf16) = X @ W — MFMA 16x16x32 bf16, f32 accumulate.
// Block: 256 thr / 4 waves, tile M=128 x N=64, K-tile 32 (8 tiles).
// Wave w owns rows [w*32, w*32+32): 2 row-subtiles x 4 col-subtiles = 8 acc.
// LDS: XsT[4][128][8] bf16 (k-group-major, 16B rows) + WtT[32][64][8] bf16
//   (WtT[kg][c][e] = W[kg*8+e][c]) = 40960 B exactly -> 4 blocks/CU.
// Fragment reads are 16B-aligned ds_read_b128, bank=4*(lane&15)%32 ->
// 2 lanes/bank-quad per 16-lane phase = conflict-free.
// Next K-tile global loads issued before MFMA to hide HBM latency.
// ---------------------------------------------------------------------------
__global__ __launch_bounds__(256, 4) void gemm_xw_mfma(const float* __restrict__ X,
                                                       const float* __restrict__ W,
                                                       ushort* __restrict__ support) {
    __shared__ ushort XsT[4][128][8];   // [k-group][row][8 k]  (8 KB)
    __shared__ ushort WtT[32][64][8];   // [k-group over all K][col][8 k] (32 KB)

    const int t = threadIdx.x;
    const int row0 = blockIdx.x * 128;
    const int lane = t & 63;
    const int w = t >> 6;
    const int lr = lane & 15;
    const int lg = lane >> 4;

    // ---- stage all of W (bf16, transposed to k-major-per-col) -------------
#pragma unroll
    for (int p = 0; p < 16; ++p) {
        int idx = t + p * 256;          // 0..4095
        int k   = idx >> 4;             // 0..255
        int c4  = idx & 15;             // float4 index along N
        float4 v = *reinterpret_cast<const float4*>(W + (size_t)k * D_OUT + c4 * 4);
        WtT[k >> 3][c4 * 4 + 0][k & 7] = f32_to_bf16_rne(v.x);
        WtT[k >> 3][c4 * 4 + 1][k & 7] = f32_to_bf16_rne(v.y);
        WtT[k >> 3][c4 * 4 + 2][k & 7] = f32_to_bf16_rne(v.z);
        WtT[k >> 3][c4 * 4 + 3][k & 7] = f32_to_bf16_rne(v.w);
    }

    // ---- X staging thread->element mapping (constant across k-tiles) ------
    int  xrow[4], xq[4];
    bool xval[4];
#pragma unroll
    for (int p = 0; p < 4; ++p) {
        int idx = t + p * 256;          // 0..1023
        xrow[p] = idx >> 3;             // 0..127
        xq[p]   = idx & 7;              // float4 index within 32-k slab
        xval[p] = (row0 + xrow[p]) < N_NODES;
    }

    float4 xreg[4];
#pragma unroll
    for (int p = 0; p < 4; ++p) {
        xreg[p] = make_float4(0.f, 0.f, 0.f, 0.f);
        if (xval[p])
            xreg[p] = *reinterpret_cast<const float4*>(
                X + (size_t)(row0 + xrow[p]) * D_IN + 0 * 32 + xq[p] * 4);
    }

    f32x4 acc[2][4];
#pragma unroll
    for (int mi = 0; mi < 2; ++mi)
#pragma unroll
        for (int ni = 0; ni < 4; ++ni) acc[mi][ni] = (f32x4){0.f, 0.f, 0.f, 0.f};

    for (int kt = 0; kt < 8; ++kt) {
        // write staged X (bf16) for this k-tile
#pragma unroll
        for (int p = 0; p < 4; ++p) {
            uint2 u;
            u.x = pack2bf(xreg[p].x, xreg[p].y);
            u.y = pack2bf(xreg[p].z, xreg[p].w);
            *reinterpret_cast<uint2*>(&XsT[xq[p] >> 1][xrow[p]][(xq[p] & 1) * 4]) = u;
        }
        __syncthreads();

        // prefetch next k-tile while MFMAs run
        if (kt < 7) {
#pragma unroll
            for (int p = 0; p < 4; ++p) {
                if (xval[p])
                    xreg[p] = *reinterpret_cast<const float4*>(
                        X + (size_t)(row0 + xrow[p]) * D_IN + (kt + 1) * 32 + xq[p] * 4);
            }
        }

        bf16x8 a0 = *reinterpret_cast<const bf16x8*>(&XsT[lg][w * 32 + lr][0]);
        bf16x8 a1 = *reinterpret_cast<const bf16x8*>(&XsT[lg][w * 32 + 16 + lr][0]);
#pragma unroll
        for (int ni = 0; ni < 4; ++ni) {
            bf16x8 b = *reinterpret_cast<const bf16x8*>(&WtT[kt * 4 + lg][ni * 16 + lr][0]);
            acc[0][ni] = __builtin_amdgcn_mfma_f32_16x16x32_bf16(a0, b, acc[0][ni], 0, 0, 0);
            acc[1][ni] = __builtin_amdgcn_mfma_f32_16x16x32_bf16(a1, b, acc[1][ni], 0, 0, 0);
        }
        __syncthreads();
    }

    // ---- C write: D row = lg*4+reg, col = lr (m89-verified layout) --------
#pragma unroll
    for (int mi = 0; mi < 2; ++mi) {
#pragma unroll
        for (int reg = 0; reg < 4; ++reg) {
            int grow = row0 + w * 32 + mi * 16 + lg * 4 + reg;
            if (grow < N_NODES) {
#pragma unroll
                for (int ni = 0; ni < 4; ++ni)
                    support[(size_t)grow * D_OUT + ni * 16 + lr] =
                        f32_to_bf16_rne(acc[mi][ni][reg]);
            }
        }
    }
}

// ---------------------------------------------------------------------------
// CSR build (unchanged)
// ---------------------------------------------------------------------------
__global__ void zero_ints(int* __restrict__ a, int n) {
    int i = blockIdx.x * blockDim.x + threadIdx.x;
    int stride = gridDim.x * blockDim.x;
    for (; i < n; i += stride) a[i] = 0;
}

__global__ void hist_rows(const int* __restrict__ rows, int* __restrict__ counts) {
    int i = blockIdx.x * blockDim.x + threadIdx.x;
    int stride = gridDim.x * blockDim.x;
    for (; i < N_EDGES; i += stride) atomicAdd(&counts[rows[i]], 1);
}

__global__ __launch_bounds__(256) void scan_l1(const int* __restrict__ counts,
                                               int* __restrict__ row_start,
                                               int* __restrict__ blkSums) {
    __shared__ int s[256];
    const int t = threadIdx.x;
    const int i = blockIdx.x * 256 + t;
    int v = (i < N_NODES) ? counts[i] : 0;
    s[t] = v;
    __syncthreads();
#pragma unroll
    for (int off = 1; off < 256; off <<= 1) {
        int x = (t >= off) ? s[t - off] : 0;
        __syncthreads();
        s[t] += x;
        __syncthreads();
    }
    if (i < N_NODES) row_start[i] = s[t] - v;
    if (t == 255) blkSums[blockIdx.x] = s[255];
}

__global__ __launch_bounds__(512) void scan_l2(int* __restrict__ blkSums, int nblk) {
    __shared__ int s[512];
    const int t = threadIdx.x;
    int v = (t < nblk) ? blkSums[t] : 0;
    s[t] = v;
    __syncthreads();
#pragma unroll
    for (int off = 1; off < 512; off <<= 1) {
        int x = (t >= off) ? s[t - off] : 0;
        __syncthreads();
        s[t] += x;
        __syncthreads();
    }
    if (t < nblk) blkSums[t] = s[t] - v;
}

__global__ __launch_bounds__(256) void scan_l3(int* __restrict__ row_start,
                                               const int* __restrict__ blkSums) {
    const int i = blockIdx.x * 256 + threadIdx.x;
    if (i < N_NODES) row_start[i] += blkSums[blockIdx.x];
    if (i == 0) row_start[N_NODES] = N_EDGES;
}

__global__ void reorder_edges(const int* __restrict__ rows,
                              const int* __restrict__ cols,
                              const float* __restrict__ vals,
                              const int* __restrict__ row_start,
                              int* __restrict__ fill,
                              uint2* __restrict__ edge_s) {
    int i = blockIdx.x * blockDim.x + threadIdx.x;
    int stride = gridDim.x * blockDim.x;
    for (; i < N_EDGES; i += stride) {
        int r = rows[i];
        int pos = row_start[r] + atomicAdd(&fill[r], 1);
        edge_s[pos] = make_uint2((unsigned)cols[i], __float_as_uint(vals[i]));
    }
}

// ---------------------------------------------------------------------------
// Gather: one wave per output row (unchanged).
// ---------------------------------------------------------------------------
__global__ __launch_bounds__(256) void spmm_gather(const uint2* __restrict__ edge_s,
                                                   const int* __restrict__ row_start,
                                                   const ushort* __restrict__ support,
                                                   float* __restrict__ out) {
    const int r = blockIdx.x * 4 + (threadIdx.x >> 6);
    if (r >= N_NODES) return;
    const int lane = threadIdx.x & 63;

    int e   = row_start[r];
    int end = row_start[r + 1];
    float acc = 0.0f;

    for (; e + 1 < end; e += 2) {
        uint2 p0 = edge_s[e];
        uint2 p1 = edge_s[e + 1];
        float s0 = bf16_to_f32(support[(size_t)p0.x * D_OUT + lane]);
        float s1 = bf16_to_f32(support[(size_t)p1.x * D_OUT + lane]);
        acc = fmaf(__uint_as_float(p0.y), s0, acc);
        acc = fmaf(__uint_as_float(p1.y), s1, acc);
    }
    if (e < end) {
        uint2 p = edge_s[e];
        acc = fmaf(__uint_as_float(p.y), bf16_to_f32(support[(size_t)p.x * D_OUT + lane]), acc);
    }
    out[(size_t)r * D_OUT + lane] = acc;
}

// ---------------------------------------------------------------------------
// Fallback path (ws too small): zero + atomic scatter from bf16 support.
// ---------------------------------------------------------------------------
__global__ void zero_out(float4* __restrict__ out, int n4) {
    int i = blockIdx.x * blockDim.x + threadIdx.x;
    int stride = gridDim.x * blockDim.x;
    for (; i < n4; i += stride) out[i] = float4{0.0f, 0.0f, 0.0f, 0.0f};
}

__global__ __launch_bounds__(256) void spmm_scatter(const int* __restrict__ rows,
                                                    const int* __restrict__ cols,
                                                    const float* __restrict__ vals,
                                                    const ushort* __restrict__ support,
                                                    float* __restrict__ out,
                                                    int n_edges) {
    const int lane = threadIdx.x & 63;
    const int wave_global = (int)((blockIdx.x * blockDim.x + threadIdx.x) >> 6);
    const int n_waves = (int)((gridDim.x * blockDim.x) >> 6);

    for (int base = wave_global * 64; base < n_edges; base += n_waves * 64) {
        int my_e = base + lane;
        int r = rows[my_e];
        int c = cols[my_e];
        float v = vals[my_e];

        int cnt = min(64, n_edges - base);
        for (int i = 0; i < cnt; ++i) {
            int row = __shfl(r, i);
            int col = __shfl(c, i);
            float val = __shfl(v, i);
            float s = bf16_to_f32(support[(size_t)col * D_OUT + lane]);
            atomicAdd(&out[(size_t)row * D_OUT + lane], val * s);
        }
    }
}

extern "C" void kernel_launch(void* const* d_in, const int* in_sizes, int n_in,
                              void* d_out, int out_size, void* d_ws, size_t ws_size,
                              hipStream_t stream) {
    const float* X      = (const float*)d_in[0];
    const float* W      = (const float*)d_in[1];
    const int*   A_rows = (const int*)d_in[2];
    const int*   A_cols = (const int*)d_in[3];
    const float* A_vals = (const float*)d_in[4];
    float* out = (float*)d_out;

    char* ws = (char*)d_ws;
    ushort* support = (ushort*)(ws + OFF_SUPPORT);

    const int gemm_blocks = (N_NODES + 127) / 128;  // 782

    if (ws_size >= (size_t)WS_NEEDED) {
        int*   row_start = (int*)(ws + OFF_ROWSTART);
        int*   counts    = (int*)(ws + OFF_COUNTS);
        int*   fill      = (int*)(ws + OFF_FILL);
        uint2* edge_s    = (uint2*)(ws + OFF_EDGES);
        int*   blkSums   = (int*)(ws + OFF_BLKSUMS);

        const int nblk_scan = (N_NODES + 255) / 256;  // 391

        // CSR build
        zero_ints<<<256, 256, 0, stream>>>(counts, 2 * 400000 / 4);  // counts+fill
        hist_rows<<<1024, 256, 0, stream>>>(A_rows, counts);
        scan_l1<<<nblk_scan, 256, 0, stream>>>(counts, row_start, blkSums);
        scan_l2<<<1, 512, 0, stream>>>(blkSums, nblk_scan);
        scan_l3<<<nblk_scan, 256, 0, stream>>>(row_start, blkSums);
        reorder_edges<<<1024, 256, 0, stream>>>(A_rows, A_cols, A_vals, row_start,
                                                fill, edge_s);

        // support = bf16(X @ W)  (MFMA)
        gemm_xw_mfma<<<gemm_blocks, 256, 0, stream>>>(X, W, support);

        // out = A @ support (gather, no atomics)
        spmm_gather<<<(N_NODES + 3) / 4, 256, 0, stream>>>(edge_s, row_start,
                                                           support, out);
    } else {
        int n4 = (N_NODES * D_OUT) / 4;
        zero_out<<<2048, 256, 0, stream>>>((float4*)out, n4);
        gemm_xw_mfma<<<gemm_blocks, 256, 0, stream>>>(X, W, support);
        int chunks = N_EDGES / 64;
        spmm_scatter<<<(chunks + 3) / 4, 256, 0, stream>>>(A_rows, A_cols, A_vals,
                                                           support, out, N_EDGES);
    }
}